// Round 2
// baseline (1912.176 us; speedup 1.0000x reference)
//
#include <hip/hip_runtime.h>
#include <hip/hip_bf16.h>
#include <cstdint>

#define BN_EPS 1e-5f

__device__ inline void fatomadd(float* p, float v) { unsafeAtomicAdd(p, v); }

__device__ inline unsigned short f2bf(float f) {
  unsigned int b = __float_as_uint(f);
  b += 0x7FFFu + ((b >> 16) & 1u);  // RNE
  return (unsigned short)(b >> 16);
}
__device__ inline float bf2f(unsigned short u) { return __uint_as_float((unsigned int)u << 16); }

// ---------------- pack weights ----------------
// B1: (32 x 640): col c<512 -> o=c>>3,k=c&7 : W1[k,i,o]; 512..575 root1; 576..639 Wskip
__global__ void pack_b1(const float* __restrict__ W1, const float* __restrict__ root1,
                        const float* __restrict__ Wskip, float* __restrict__ B1) {
  int idx = blockIdx.x * blockDim.x + threadIdx.x;
  if (idx >= 32 * 640) return;
  int i = idx / 640, c = idx % 640;
  float v;
  if (c < 512) { int o = c >> 3, k = c & 7; v = W1[k * (32 * 64) + i * 64 + o]; }
  else if (c < 576) v = root1[i * 64 + (c - 512)];
  else v = Wskip[i * 64 + (c - 576)];
  B1[idx] = v;
}

// B2: (64 x 576): col c<512 -> o=c>>3,k=c&7 : W2[k,i,o]; 512..575 root2
__global__ void pack_b2(const float* __restrict__ W2, const float* __restrict__ root2,
                        float* __restrict__ B2) {
  int idx = blockIdx.x * blockDim.x + threadIdx.x;
  if (idx >= 64 * 576) return;
  int i = idx / 576, c = idx % 576;
  float v;
  if (c < 512) { int o = c >> 3, k = c & 7; v = W2[k * (64 * 64) + i * 64 + o]; }
  else v = root2[i * 64 + (c - 512)];
  B2[idx] = v;
}

// ---------------- small GEMM: C(M x Ncols bf16) = A(M x K fp32) @ B(K x Ncols fp32) ----------------
// optional fused bn+elu on A elements (layer-2 input h = elu(bn1(hpre1)))
template <int K>
__global__ __launch_bounds__(256) void gemm_nk(const float* __restrict__ A,
                                               const float* __restrict__ B,
                                               __hip_bfloat16* __restrict__ C, int M, int Ncols,
                                               const float* __restrict__ scale,
                                               const float* __restrict__ shift) {
  __shared__ float As[64][K];
  __shared__ float Bs[K][64];
  const int tid = threadIdx.x;
  const int row0 = blockIdx.x * 64;
  const int col0 = blockIdx.y * 64;

  for (int idx = tid; idx < 64 * K; idx += 256) {
    int r = idx / K, k = idx - r * K;
    int gr = row0 + r;
    float v = 0.f;
    if (gr < M) v = A[(size_t)gr * K + k];
    if (scale) { v = v * scale[k] + shift[k]; v = v > 0.f ? v : expm1f(v); }
    As[r][k] = v;
  }
  for (int idx = tid; idx < 64 * K; idx += 256) {
    int k = idx >> 6, n = idx & 63;
    Bs[k][n] = B[(size_t)k * Ncols + col0 + n];
  }
  __syncthreads();

  const int r0 = (tid >> 4) << 2;
  const int c0 = (tid & 15) << 2;
  float acc[4][4];
#pragma unroll
  for (int i = 0; i < 4; i++)
#pragma unroll
    for (int j = 0; j < 4; j++) acc[i][j] = 0.f;

#pragma unroll
  for (int k = 0; k < K; k += 4) {
    float4 a0 = *(const float4*)&As[r0 + 0][k];
    float4 a1 = *(const float4*)&As[r0 + 1][k];
    float4 a2 = *(const float4*)&As[r0 + 2][k];
    float4 a3 = *(const float4*)&As[r0 + 3][k];
    float4 b0 = *(const float4*)&Bs[k + 0][c0];
    float4 b1 = *(const float4*)&Bs[k + 1][c0];
    float4 b2 = *(const float4*)&Bs[k + 2][c0];
    float4 b3 = *(const float4*)&Bs[k + 3][c0];
    float av[4][4] = {{a0.x, a0.y, a0.z, a0.w},
                      {a1.x, a1.y, a1.z, a1.w},
                      {a2.x, a2.y, a2.z, a2.w},
                      {a3.x, a3.y, a3.z, a3.w}};
    float bv[4][4] = {{b0.x, b0.y, b0.z, b0.w},
                      {b1.x, b1.y, b1.z, b1.w},
                      {b2.x, b2.y, b2.z, b2.w},
                      {b3.x, b3.y, b3.z, b3.w}};
#pragma unroll
    for (int kk = 0; kk < 4; kk++)
#pragma unroll
      for (int i = 0; i < 4; i++)
#pragma unroll
        for (int j = 0; j < 4; j++) acc[i][j] += av[i][kk] * bv[kk][j];
  }

#pragma unroll
  for (int i = 0; i < 4; i++) {
    int gr = row0 + r0 + i;
    if (gr < M) {
      ushort4 pk;
      pk.x = f2bf(acc[i][0]);
      pk.y = f2bf(acc[i][1]);
      pk.z = f2bf(acc[i][2]);
      pk.w = f2bf(acc[i][3]);
      *(ushort4*)&C[(size_t)gr * Ncols + col0 + c0] = pk;
    }
  }
}

// ---------------- per-edge message: one wave per edge, Y is bf16 [n][o*8+k] ----------------
template <bool COUNT>
__global__ __launch_bounds__(256) void msg_kernel(const __hip_bfloat16* __restrict__ Y, int ystride,
                                                  const int* __restrict__ ei,
                                                  const float* __restrict__ attr, int E,
                                                  float* __restrict__ agg,
                                                  float* __restrict__ cnt) {
  long long gid = (long long)blockIdx.x * blockDim.x + threadIdx.x;
  int e = (int)(gid >> 6);
  if (e >= E) return;
  int lane = (int)(gid & 63);
  int src = ei[e];
  int dst = ei[E + e];
  float u0 = attr[3 * e + 0], u1 = attr[3 * e + 1], u2 = attr[3 * e + 2];
  float p0 = 1.f - u0, p1 = 1.f - u1, p2 = 1.f - u2;
  float w[8];
  w[0] = p0 * p1 * p2; w[1] = u0 * p1 * p2;
  w[2] = p0 * u1 * p2; w[3] = u0 * u1 * p2;
  w[4] = p0 * p1 * u2; w[5] = u0 * p1 * u2;
  w[6] = p0 * u1 * u2; w[7] = u0 * u1 * u2;
  const __hip_bfloat16* yr = Y + (size_t)src * ystride + lane * 8;
  union { float4 f4; unsigned short us[8]; } u;
  u.f4 = *(const float4*)yr;  // 16B: 8 bf16 (k=0..7 for this lane's output channel)
  float m = 0.f;
#pragma unroll
  for (int k = 0; k < 8; k++) m += w[k] * bf2f(u.us[k]);
  fatomadd(&agg[(size_t)dst * 64 + lane], m);
  if (COUNT && lane == 0) fatomadd(&cnt[dst], 1.f);
}

// ---------------- finish layer1 (in-place): agg <- agg/cnt + root1term; spre(d_out) <- skipterm; stats ----------------
__global__ __launch_bounds__(256) void finish1(float* __restrict__ agg,
                                               const float* __restrict__ cnt,
                                               const __hip_bfloat16* __restrict__ ybuf, int N,
                                               float* __restrict__ spre,
                                               double* __restrict__ sums /* 4x64 */) {
  int tid = threadIdx.x;
  int ch = tid & 63, slot = tid >> 6;
  float sh = 0.f, sh2 = 0.f, ss = 0.f, ss2 = 0.f;
  for (int n = blockIdx.x * 4 + slot; n < N; n += gridDim.x * 4) {
    float inv = 1.f / fmaxf(cnt[n], 1.f);
    float h = agg[(size_t)n * 64 + ch] * inv + bf2f(((const unsigned short*)ybuf)[(size_t)n * 640 + 512 + ch]);
    float s = bf2f(((const unsigned short*)ybuf)[(size_t)n * 640 + 576 + ch]);
    agg[(size_t)n * 64 + ch] = h;
    spre[(size_t)n * 64 + ch] = s;
    sh += h; sh2 += h * h; ss += s; ss2 += s * s;
  }
  __shared__ float red[256];
  float vals[4] = {sh, sh2, ss, ss2};
  for (int v = 0; v < 4; v++) {
    __syncthreads();
    red[tid] = vals[v];
    __syncthreads();
    if (tid < 64) {
      float tot = red[tid] + red[tid + 64] + red[tid + 128] + red[tid + 192];
      atomicAdd(&sums[v * 64 + tid], (double)tot);
    }
  }
}

// ---------------- finish layer2 (in-place): agg <- agg/cnt + root2term; stats ----------------
__global__ __launch_bounds__(256) void finish2(float* __restrict__ agg,
                                               const float* __restrict__ cnt,
                                               const __hip_bfloat16* __restrict__ ybuf, int N,
                                               double* __restrict__ sums /* 2x64 */) {
  int tid = threadIdx.x;
  int ch = tid & 63, slot = tid >> 6;
  float sh = 0.f, sh2 = 0.f;
  for (int n = blockIdx.x * 4 + slot; n < N; n += gridDim.x * 4) {
    float inv = 1.f / fmaxf(cnt[n], 1.f);
    float h = agg[(size_t)n * 64 + ch] * inv + bf2f(((const unsigned short*)ybuf)[(size_t)n * 576 + 512 + ch]);
    agg[(size_t)n * 64 + ch] = h;
    sh += h; sh2 += h * h;
  }
  __shared__ float red[256];
  float vals[2] = {sh, sh2};
  for (int v = 0; v < 2; v++) {
    __syncthreads();
    red[tid] = vals[v];
    __syncthreads();
    if (tid < 64) {
      float tot = red[tid] + red[tid + 64] + red[tid + 128] + red[tid + 192];
      atomicAdd(&sums[v * 64 + tid], (double)tot);
    }
  }
}

// ---------------- bn finalize ----------------
__global__ void bn_finalize(const double* __restrict__ sums /*2x64*/, const float* __restrict__ g,
                            const float* __restrict__ b, float* __restrict__ scale,
                            float* __restrict__ shift, int N) {
  int t = threadIdx.x;
  if (t >= 64) return;
  double mean = sums[t] / (double)N;
  double var = sums[64 + t] / (double)N - mean * mean;
  double inv = 1.0 / sqrt(var + (double)BN_EPS);
  float sc = (float)((double)g[t] * inv);
  scale[t] = sc;
  shift[t] = b[t] - (float)mean * sc;
}

// ---------------- epilogue: out = elu(bn2(h2pre) + bnS(spre)); spre lives in d_out, overwritten ----------------
__global__ __launch_bounds__(256) void final_k(const float* __restrict__ h2pre,
                                               const float* __restrict__ scale2,
                                               const float* __restrict__ shift2,
                                               const float* __restrict__ scaleS,
                                               const float* __restrict__ shiftS,
                                               float* __restrict__ out, int total) {
  int idx = blockIdx.x * 256 + threadIdx.x;
  if (idx >= total) return;
  int ch = idx & 63;
  float h2 = h2pre[idx] * scale2[ch] + shift2[ch];
  float s = out[idx] * scaleS[ch] + shiftS[ch];
  float v = h2 + s;
  out[idx] = v > 0.f ? v : expm1f(v);
}

extern "C" void kernel_launch(void* const* d_in, const int* in_sizes, int n_in,
                              void* d_out, int out_size, void* d_ws, size_t ws_size,
                              hipStream_t stream) {
  const float* x     = (const float*)d_in[0];
  const int*   ei    = (const int*)d_in[1];
  const float* attr  = (const float*)d_in[2];
  const float* W1    = (const float*)d_in[3];
  const float* root1 = (const float*)d_in[4];
  const float* g1    = (const float*)d_in[5];
  const float* b1    = (const float*)d_in[6];
  const float* W2    = (const float*)d_in[7];
  const float* root2 = (const float*)d_in[8];
  const float* g2    = (const float*)d_in[9];
  const float* b2    = (const float*)d_in[10];
  const float* Wskip = (const float*)d_in[11];
  const float* gS    = (const float*)d_in[12];
  const float* bS    = (const float*)d_in[13];
  const int N = in_sizes[0] / 32;
  const int E = in_sizes[1] / 2;
  float* out = (float*)d_out;

  char* ws = (char*)d_ws;
  size_t off = 0;
  auto alloc = [&](size_t bytes) {
    void* p = ws + off;
    off = (off + bytes + 255) & ~(size_t)255;
    return p;
  };
  float*  B1     = (float*)alloc(32 * 640 * 4);
  float*  B2     = (float*)alloc(64 * 576 * 4);
  double* sums   = (double*)alloc(6 * 64 * 8);
  float*  scales = (float*)alloc(6 * 64 * 4);
  float*  cnt    = (float*)alloc((size_t)N * 4);
  float*  agg    = (float*)alloc((size_t)N * 64 * 4);           // also hpre1, then h2pre (in place)
  __hip_bfloat16* ybuf = (__hip_bfloat16*)alloc((size_t)N * 640 * 2);  // Y1ext(640) then Y2ext(576)
  if (off > ws_size) return;  // workspace too small: fail gracefully, no OOB fault

  hipMemsetAsync(cnt, 0, (size_t)N * 4, stream);
  hipMemsetAsync(agg, 0, (size_t)N * 64 * 4, stream);
  hipMemsetAsync(sums, 0, 6 * 64 * 8, stream);

  pack_b1<<<(32 * 640 + 255) / 256, 256, 0, stream>>>(W1, root1, Wskip, B1);
  pack_b2<<<(64 * 576 + 255) / 256, 256, 0, stream>>>(W2, root2, B2);

  // layer 1: Y1ext = x @ [W1(o-major)|root1|Wskip]   (N x 640, bf16)
  dim3 grid1((N + 63) / 64, 10);
  gemm_nk<32><<<grid1, 256, 0, stream>>>(x, B1, ybuf, N, 640, nullptr, nullptr);

  long long mthreads = (long long)E * 64;
  int mblocks = (int)((mthreads + 255) / 256);
  msg_kernel<true><<<mblocks, 256, 0, stream>>>(ybuf, 640, ei, attr, E, agg, cnt);

  finish1<<<1024, 256, 0, stream>>>(agg, cnt, ybuf, N, out, sums);
  bn_finalize<<<1, 64, 0, stream>>>(sums + 0 * 64, g1, b1, scales + 0 * 64, scales + 1 * 64, N);
  bn_finalize<<<1, 64, 0, stream>>>(sums + 2 * 64, gS, bS, scales + 2 * 64, scales + 3 * 64, N);

  // layer 2: Y2ext = elu(bn1(hpre)) @ [W2(o-major)|root2]   (N x 576, bf16)
  dim3 grid2((N + 63) / 64, 9);
  gemm_nk<64><<<grid2, 256, 0, stream>>>(agg, B2, ybuf, N, 576, scales + 0 * 64, scales + 1 * 64);

  hipMemsetAsync(agg, 0, (size_t)N * 64 * 4, stream);
  msg_kernel<false><<<mblocks, 256, 0, stream>>>(ybuf, 576, ei, attr, E, agg, nullptr);

  finish2<<<1024, 256, 0, stream>>>(agg, cnt, ybuf, N, sums + 4 * 64);
  bn_finalize<<<1, 64, 0, stream>>>(sums + 4 * 64, g2, b2, scales + 4 * 64, scales + 5 * 64, N);

  final_k<<<((N * 64) + 255) / 256, 256, 0, stream>>>(agg, scales + 4 * 64, scales + 5 * 64,
                                                      scales + 2 * 64, scales + 3 * 64, out,
                                                      N * 64);
}

// Round 3
// 1112.813 us; speedup vs baseline: 1.7183x; 1.7183x over previous
//
#include <hip/hip_runtime.h>
#include <hip/hip_bf16.h>
#include <cstdint>

#define BN_EPS 1e-5f

typedef __attribute__((ext_vector_type(8))) short bf16x8;
typedef __attribute__((ext_vector_type(4))) float f32x4;

__device__ inline void fatomadd(float* p, float v) { unsafeAtomicAdd(p, v); }

__device__ inline unsigned short f2bf(float f) {
  unsigned int b = __float_as_uint(f);
  b += 0x7FFFu + ((b >> 16) & 1u);  // RNE
  return (unsigned short)(b >> 16);
}
__device__ inline float bf2f(unsigned short u) { return __uint_as_float((unsigned int)u << 16); }

// ---------------- pack weights: bf16, transposed [Ncols][K] ----------------
// col n<512 -> o=n>>3,k=n&7 : W[k,i,o]; then root (and Wskip for B1)
__global__ void pack_b1t(const float* __restrict__ W1, const float* __restrict__ root1,
                         const float* __restrict__ Wskip, __hip_bfloat16* __restrict__ B1t) {
  int idx = blockIdx.x * blockDim.x + threadIdx.x;
  if (idx >= 640 * 32) return;
  int n = idx >> 5, k = idx & 31;
  float v;
  if (n < 512) v = W1[(n & 7) * (32 * 64) + k * 64 + (n >> 3)];
  else if (n < 576) v = root1[k * 64 + (n - 512)];
  else v = Wskip[k * 64 + (n - 576)];
  ((unsigned short*)B1t)[idx] = f2bf(v);
}

__global__ void pack_b2t(const float* __restrict__ W2, const float* __restrict__ root2,
                         __hip_bfloat16* __restrict__ B2t) {
  int idx = blockIdx.x * blockDim.x + threadIdx.x;
  if (idx >= 576 * 64) return;
  int n = idx >> 6, k = idx & 63;
  float v;
  if (n < 512) v = W2[(n & 7) * (64 * 64) + k * 64 + (n >> 3)];
  else v = root2[k * 64 + (n - 512)];
  ((unsigned short*)B2t)[idx] = f2bf(v);
}

// ---------------- MFMA GEMM: C(M x Ncols bf16) = A(M x K fp32) @ Bt(Ncols x K bf16)^T ----------
// No LDS. Wave = 16 rows; block = 4 waves = 64 rows. Per 16-col tile: K/32 MFMAs.
// BN=true applies per-column bn scale/shift + ELU to A (layer-2 input).
template <int K, bool BN>
__global__ __launch_bounds__(256) void gemm_mfma(const float* __restrict__ A,
                                                 const __hip_bfloat16* __restrict__ Bt,
                                                 __hip_bfloat16* __restrict__ C, int M, int Ncols,
                                                 const float* __restrict__ scale,
                                                 const float* __restrict__ shift) {
  const int tid = threadIdx.x;
  const int lane = tid & 63;
  const int wv = tid >> 6;
  const int rowbase = blockIdx.x * 64 + wv * 16;
  const int m = lane & 15;
  const int quad = lane >> 4;
  const int k0 = quad * 8;

  int ar = rowbase + m;
  if (ar > M - 1) ar = M - 1;
  const float* arow = A + (size_t)ar * K;

  bf16x8 afrag[K / 32];
#pragma unroll
  for (int f = 0; f < K / 32; f++) {
    float v[8];
#pragma unroll
    for (int j = 0; j < 8; j++) v[j] = arow[f * 32 + k0 + j];
    if (BN) {
#pragma unroll
      for (int j = 0; j < 8; j++) {
        float t = v[j] * scale[f * 32 + k0 + j] + shift[f * 32 + k0 + j];
        v[j] = t > 0.f ? t : expm1f(t);
      }
    }
    bf16x8 af;
#pragma unroll
    for (int j = 0; j < 8; j++) af[j] = (short)f2bf(v[j]);
    afrag[f] = af;
  }

  for (int col0 = 0; col0 < Ncols; col0 += 16) {
    f32x4 acc = {0.f, 0.f, 0.f, 0.f};
#pragma unroll
    for (int f = 0; f < K / 32; f++) {
      const __hip_bfloat16* bp = Bt + (size_t)(col0 + m) * K + f * 32 + k0;
      bf16x8 bfrag = *(const bf16x8*)bp;
      acc = __builtin_amdgcn_mfma_f32_16x16x32_bf16(afrag[f], bfrag, acc, 0, 0, 0);
    }
#pragma unroll
    for (int r = 0; r < 4; r++) {
      int gr = rowbase + quad * 4 + r;
      if (gr < M) ((unsigned short*)C)[(size_t)gr * Ncols + col0 + m] = f2bf(acc[r]);
    }
  }
}

// ---------------- per-edge message: one wave per edge, Y is bf16 [n][o*8+k] ----------------
template <bool COUNT>
__global__ __launch_bounds__(256) void msg_kernel(const __hip_bfloat16* __restrict__ Y, int ystride,
                                                  const int* __restrict__ ei,
                                                  const float* __restrict__ attr, int E,
                                                  float* __restrict__ agg,
                                                  float* __restrict__ cnt) {
  long long gid = (long long)blockIdx.x * blockDim.x + threadIdx.x;
  int e = (int)(gid >> 6);
  if (e >= E) return;
  int lane = (int)(gid & 63);
  int src = ei[e];
  int dst = ei[E + e];
  float u0 = attr[3 * e + 0], u1 = attr[3 * e + 1], u2 = attr[3 * e + 2];
  float p0 = 1.f - u0, p1 = 1.f - u1, p2 = 1.f - u2;
  float w[8];
  w[0] = p0 * p1 * p2; w[1] = u0 * p1 * p2;
  w[2] = p0 * u1 * p2; w[3] = u0 * u1 * p2;
  w[4] = p0 * p1 * u2; w[5] = u0 * p1 * u2;
  w[6] = p0 * u1 * u2; w[7] = u0 * u1 * u2;
  const __hip_bfloat16* yr = Y + (size_t)src * ystride + lane * 8;
  union { float4 f4; unsigned short us[8]; } u;
  u.f4 = *(const float4*)yr;
  float m = 0.f;
#pragma unroll
  for (int k = 0; k < 8; k++) m += w[k] * bf2f(u.us[k]);
  fatomadd(&agg[(size_t)dst * 64 + lane], m);
  if (COUNT && lane == 0) fatomadd(&cnt[dst], 1.f);
}

// ---------------- finish layer1 (in-place) ----------------
__global__ __launch_bounds__(256) void finish1(float* __restrict__ agg,
                                               const float* __restrict__ cnt,
                                               const __hip_bfloat16* __restrict__ ybuf, int N,
                                               float* __restrict__ spre,
                                               double* __restrict__ sums /* 4x64 */) {
  int tid = threadIdx.x;
  int ch = tid & 63, slot = tid >> 6;
  float sh = 0.f, sh2 = 0.f, ss = 0.f, ss2 = 0.f;
  for (int n = blockIdx.x * 4 + slot; n < N; n += gridDim.x * 4) {
    float inv = 1.f / fmaxf(cnt[n], 1.f);
    float h = agg[(size_t)n * 64 + ch] * inv + bf2f(((const unsigned short*)ybuf)[(size_t)n * 640 + 512 + ch]);
    float s = bf2f(((const unsigned short*)ybuf)[(size_t)n * 640 + 576 + ch]);
    agg[(size_t)n * 64 + ch] = h;
    spre[(size_t)n * 64 + ch] = s;
    sh += h; sh2 += h * h; ss += s; ss2 += s * s;
  }
  __shared__ float red[256];
  float vals[4] = {sh, sh2, ss, ss2};
  for (int v = 0; v < 4; v++) {
    __syncthreads();
    red[tid] = vals[v];
    __syncthreads();
    if (tid < 64) {
      float tot = red[tid] + red[tid + 64] + red[tid + 128] + red[tid + 192];
      atomicAdd(&sums[v * 64 + tid], (double)tot);
    }
  }
}

// ---------------- finish layer2 (in-place) ----------------
__global__ __launch_bounds__(256) void finish2(float* __restrict__ agg,
                                               const float* __restrict__ cnt,
                                               const __hip_bfloat16* __restrict__ ybuf, int N,
                                               double* __restrict__ sums /* 2x64 */) {
  int tid = threadIdx.x;
  int ch = tid & 63, slot = tid >> 6;
  float sh = 0.f, sh2 = 0.f;
  for (int n = blockIdx.x * 4 + slot; n < N; n += gridDim.x * 4) {
    float inv = 1.f / fmaxf(cnt[n], 1.f);
    float h = agg[(size_t)n * 64 + ch] * inv + bf2f(((const unsigned short*)ybuf)[(size_t)n * 576 + 512 + ch]);
    agg[(size_t)n * 64 + ch] = h;
    sh += h; sh2 += h * h;
  }
  __shared__ float red[256];
  float vals[2] = {sh, sh2};
  for (int v = 0; v < 2; v++) {
    __syncthreads();
    red[tid] = vals[v];
    __syncthreads();
    if (tid < 64) {
      float tot = red[tid] + red[tid + 64] + red[tid + 128] + red[tid + 192];
      atomicAdd(&sums[v * 64 + tid], (double)tot);
    }
  }
}

// ---------------- bn finalize ----------------
__global__ void bn_finalize(const double* __restrict__ sums /*2x64*/, const float* __restrict__ g,
                            const float* __restrict__ b, float* __restrict__ scale,
                            float* __restrict__ shift, int N) {
  int t = threadIdx.x;
  if (t >= 64) return;
  double mean = sums[t] / (double)N;
  double var = sums[64 + t] / (double)N - mean * mean;
  double inv = 1.0 / sqrt(var + (double)BN_EPS);
  float sc = (float)((double)g[t] * inv);
  scale[t] = sc;
  shift[t] = b[t] - (float)mean * sc;
}

// ---------------- epilogue: out = elu(bn2(h2pre) + bnS(spre)); spre lives in d_out ----------------
__global__ __launch_bounds__(256) void final_k(const float* __restrict__ h2pre,
                                               const float* __restrict__ scale2,
                                               const float* __restrict__ shift2,
                                               const float* __restrict__ scaleS,
                                               const float* __restrict__ shiftS,
                                               float* __restrict__ out, int total) {
  int idx = blockIdx.x * 256 + threadIdx.x;
  if (idx >= total) return;
  int ch = idx & 63;
  float h2 = h2pre[idx] * scale2[ch] + shift2[ch];
  float s = out[idx] * scaleS[ch] + shiftS[ch];
  float v = h2 + s;
  out[idx] = v > 0.f ? v : expm1f(v);
}

extern "C" void kernel_launch(void* const* d_in, const int* in_sizes, int n_in,
                              void* d_out, int out_size, void* d_ws, size_t ws_size,
                              hipStream_t stream) {
  const float* x     = (const float*)d_in[0];
  const int*   ei    = (const int*)d_in[1];
  const float* attr  = (const float*)d_in[2];
  const float* W1    = (const float*)d_in[3];
  const float* root1 = (const float*)d_in[4];
  const float* g1    = (const float*)d_in[5];
  const float* b1    = (const float*)d_in[6];
  const float* W2    = (const float*)d_in[7];
  const float* root2 = (const float*)d_in[8];
  const float* g2    = (const float*)d_in[9];
  const float* b2    = (const float*)d_in[10];
  const float* Wskip = (const float*)d_in[11];
  const float* gS    = (const float*)d_in[12];
  const float* bS    = (const float*)d_in[13];
  const int N = in_sizes[0] / 32;
  const int E = in_sizes[1] / 2;
  float* out = (float*)d_out;

  char* ws = (char*)d_ws;
  size_t off = 0;
  auto alloc = [&](size_t bytes) {
    void* p = ws + off;
    off = (off + bytes + 255) & ~(size_t)255;
    return p;
  };
  __hip_bfloat16* B1t = (__hip_bfloat16*)alloc(640 * 32 * 2);
  __hip_bfloat16* B2t = (__hip_bfloat16*)alloc(576 * 64 * 2);
  double* sums   = (double*)alloc(6 * 64 * 8);
  float*  scales = (float*)alloc(6 * 64 * 4);
  float*  cnt    = (float*)alloc((size_t)N * 4);
  float*  agg    = (float*)alloc((size_t)N * 64 * 4);                 // hpre1, then h2pre (in place)
  __hip_bfloat16* ybuf = (__hip_bfloat16*)alloc((size_t)N * 640 * 2); // Y1ext(640) then Y2ext(576)
  if (off > ws_size) return;  // workspace too small: fail gracefully

  hipMemsetAsync(cnt, 0, (size_t)N * 4, stream);
  hipMemsetAsync(agg, 0, (size_t)N * 64 * 4, stream);
  hipMemsetAsync(sums, 0, 6 * 64 * 8, stream);

  pack_b1t<<<(640 * 32 + 255) / 256, 256, 0, stream>>>(W1, root1, Wskip, B1t);
  pack_b2t<<<(576 * 64 + 255) / 256, 256, 0, stream>>>(W2, root2, B2t);

  const int gblocks = (N + 63) / 64;

  // layer 1: Y1ext = x @ [W1(o-major)|root1|Wskip]   (N x 640, bf16)
  gemm_mfma<32, false><<<gblocks, 256, 0, stream>>>(x, B1t, ybuf, N, 640, nullptr, nullptr);

  long long mthreads = (long long)E * 64;
  int mblocks = (int)((mthreads + 255) / 256);
  msg_kernel<true><<<mblocks, 256, 0, stream>>>(ybuf, 640, ei, attr, E, agg, cnt);

  finish1<<<1024, 256, 0, stream>>>(agg, cnt, ybuf, N, out, sums);
  bn_finalize<<<1, 64, 0, stream>>>(sums + 0 * 64, g1, b1, scales + 0 * 64, scales + 1 * 64, N);
  bn_finalize<<<1, 64, 0, stream>>>(sums + 2 * 64, gS, bS, scales + 2 * 64, scales + 3 * 64, N);

  // layer 2: Y2ext = elu(bn1(hpre)) @ [W2(o-major)|root2]   (N x 576, bf16)
  gemm_mfma<64, true><<<gblocks, 256, 0, stream>>>(agg, B2t, ybuf, N, 576, scales + 0 * 64,
                                                   scales + 1 * 64);

  hipMemsetAsync(agg, 0, (size_t)N * 64 * 4, stream);
  msg_kernel<false><<<mblocks, 256, 0, stream>>>(ybuf, 576, ei, attr, E, agg, nullptr);

  finish2<<<1024, 256, 0, stream>>>(agg, cnt, ybuf, N, sums + 4 * 64);
  bn_finalize<<<1, 64, 0, stream>>>(sums + 4 * 64, g2, b2, scales + 4 * 64, scales + 5 * 64, N);

  final_k<<<((N * 64) + 255) / 256, 256, 0, stream>>>(agg, scales + 4 * 64, scales + 5 * 64,
                                                      scales + 2 * 64, scales + 3 * 64, out,
                                                      N * 64);
}